// Round 11
// baseline (133.313 us; speedup 1.0000x reference)
//
#include <hip/hip_runtime.h>

#define NB 512
#define ND 256
#define NKQ 65536
#define LCOLS 65539            // 3 + 65536
#define QTAIL 64000            // 65536 - 1536
#define TEMP 0.07f

// d_out element offsets (f32)
#define OFF_LABELS 33555968ull // 512*65539
#define OFF_SCORE  67111936ull // 2*512*65539
#define OFF_QUEUE  67115520ull // OFF_SCORE + 512*7

typedef __attribute__((ext_vector_type(8))) _Float16 half8;
typedef __attribute__((ext_vector_type(4))) float f32x4;
typedef __attribute__((ext_vector_type(4), aligned(4))) float f32x4u;
typedef __attribute__((ext_vector_type(4))) unsigned short us4;

__device__ inline float wave_sum(float v) {
#pragma unroll
  for (int m = 1; m < 64; m <<= 1) v += __shfl_xor(v, m, 64);
  return v;
}
__device__ inline unsigned short f2bf(float x) {  // RNE f32->bf16
  union { float f; unsigned u; } v; v.f = x;
  unsigned r = (v.u + 0x7FFF + ((v.u >> 16) & 1)) >> 16;
  return (unsigned short)r;
}
__device__ inline float bf2f(unsigned short h) {
  union { unsigned u; float f; } v; v.u = ((unsigned)h) << 16;
  return v.f;
}

// ws layout (bytes):
// [0, 262144)          : fp16 normalized q in MFMA FRAGMENT ORDER
// [262144, 786432)     : f32 normalized q (row-major, for kpos)
// [786432, 788480)     : pos_min[512]
// [788480, 794624)     : score_pos[512*3]
// [1048576, 9437184)   : stat partials bf16x4 [2048 groups][512 rows]

// 512 blocks: normalize 4 rows each (query -> qfrag/qf32, key -> queue tail)
__global__ __launch_bounds__(256) void kprep(const float* __restrict__ query,
                                             const float* __restrict__ key_emb,
                                             float* __restrict__ out,
                                             _Float16* __restrict__ qfrag,
                                             float* __restrict__ qf32) {
  int blk = blockIdx.x;
  int w = threadIdx.x >> 6, l = threadIdx.x & 63;
  int r = blk * 4 + w;  // 0..2047
  const float* src = (r < NB) ? (query + (size_t)r * ND)
                              : (key_emb + (size_t)(r - NB) * ND);
  float x0 = src[l], x1 = src[l + 64], x2 = src[l + 128], x3 = src[l + 192];
  float ss = wave_sum(x0 * x0 + x1 * x1 + x2 * x2 + x3 * x3);
  float sc = 1.0f / fmaxf(sqrtf(ss), 1e-12f);
  x0 *= sc; x1 *= sc; x2 *= sc; x3 *= sc;
  if (r < NB) {
    float xs[4] = {x0, x1, x2, x3};
    int mt = r >> 4, rr = r & 15;
#pragma unroll
    for (int i = 0; i < 4; i++) {
      int d = l + i * 64;
      qf32[r * ND + d] = xs[i];
      int kk = d >> 5, g4 = (d >> 3) & 3, j = d & 7;
      qfrag[((size_t)(mt * 8 + kk) * 64 + g4 * 16 + rr) * 8 + j] = (_Float16)xs[i];
    }
  } else {
    float* dst = out + OFF_QUEUE + (size_t)(QTAIL + r - NB) * ND;
    dst[l] = x0; dst[l + 64] = x1; dst[l + 128] = x2; dst[l + 192] = x3;
  }
}

__global__ __launch_bounds__(64) void kpos(const float* __restrict__ qf32,
                                           float* __restrict__ out,
                                           float* __restrict__ posmin,
                                           float* __restrict__ spos) {
  int b = blockIdx.x, l = threadIdx.x;
  const float* q = qf32 + (size_t)b * ND;
  float q0 = q[l], q1 = q[l + 64], q2 = q[l + 128], q3 = q[l + 192];
  const float* kbase = out + OFF_QUEUE + (size_t)(QTAIL + b * 3) * ND;
  float sp[3];
#pragma unroll
  for (int j = 0; j < 3; j++) {
    const float* kp = kbase + (size_t)j * ND;
    float p = q0 * kp[l] + q1 * kp[l + 64] + q2 * kp[l + 128] + q3 * kp[l + 192];
    sp[j] = wave_sum(p);
  }
  if (l == 0) {
    float* lg = out + (size_t)b * LCOLS;
    float* lb = out + OFF_LABELS + (size_t)b * LCOLS;
    float* scr = out + OFF_SCORE + (size_t)b * 7;
#pragma unroll
    for (int j = 0; j < 3; j++) {
      lg[j] = sp[j] / TEMP;
      lb[j] = 1.0f;
      scr[4 + j] = sp[j];
      spos[b * 3 + j] = sp[j];
    }
    posmin[b] = fminf(sp[0], fminf(sp[1], sp[2]));
  }
}

// r10 structure + vectorized epilogue + fused labels stores + shuffle stats.
__global__ __launch_bounds__(256) void kgemm(const float* __restrict__ queue,
                                             const _Float16* __restrict__ qfrag,
                                             const float* __restrict__ posmin,
                                             float* __restrict__ out,
                                             unsigned short* __restrict__ partials) {
  __shared__ __align__(16) float ot[4][16 * 36];  // per-wave private regions
  int blk = ((int)blockIdx.x & 7) * 64 + ((int)blockIdx.x >> 3);
  int nbase = blk * 128;
  int tid = threadIdx.x;
  int w = tid >> 6, l = tid & 63;
  int r = l & 15, g4 = l >> 4;
  float* otw = ot[w];

  // Phase 0: fused FIFO copy of this block's 128 queue rows (warms L2)
  const f32x4* qp = (const f32x4*)queue;
  f32x4* nq = (f32x4*)(out + OFF_QUEUE);
#pragma unroll
  for (int i = 0; i < 32; i++) {
    int idx = tid + i * 256;          // 128 rows * 64 f32x4
    int row = idx >> 6, c4 = idx & 63;
    int grow = nbase + row;
    f32x4 v = qp[(size_t)grow * 64 + c4];
    if (grow >= 1536)
      __builtin_nontemporal_store(v, nq + (size_t)(grow - 1536) * 64 + c4);
  }

  // Phase 1: per-wave B fragments in registers (32 cols per wave, one-time)
  uint4 bf0[8], bf1[8];
  {
    const float* qrow0 = queue + (size_t)(nbase + w * 32 + r) * ND;
    const float* qrow1 = qrow0 + 16 * ND;
#pragma unroll
    for (int kk = 0; kk < 8; kk++) {
      int k0 = kk * 32 + g4 * 8;
      f32x4 a0 = *(const f32x4*)(qrow0 + k0);
      f32x4 a1 = *(const f32x4*)(qrow0 + k0 + 4);
      f32x4 b0 = *(const f32x4*)(qrow1 + k0);
      f32x4 b1 = *(const f32x4*)(qrow1 + k0 + 4);
      half8 h0, h1;
      h0[0] = (_Float16)a0.x; h0[1] = (_Float16)a0.y; h0[2] = (_Float16)a0.z;
      h0[3] = (_Float16)a0.w; h0[4] = (_Float16)a1.x; h0[5] = (_Float16)a1.y;
      h0[6] = (_Float16)a1.z; h0[7] = (_Float16)a1.w;
      h1[0] = (_Float16)b0.x; h1[1] = (_Float16)b0.y; h1[2] = (_Float16)b0.z;
      h1[3] = (_Float16)b0.w; h1[4] = (_Float16)b1.x; h1[5] = (_Float16)b1.y;
      h1[6] = (_Float16)b1.z; h1[7] = (_Float16)b1.w;
      bf0[kk] = __builtin_bit_cast(uint4, h0);
      bf1[kk] = __builtin_bit_cast(uint4, h1);
    }
  }

  const uint4* ap = (const uint4*)qfrag;  // COALESCED: idx = (mt*8+kk)*64 + l
  const float inv_t = 1.0f / TEMP;
  int rlane = l >> 3;                     // row within 8-row group
  int cchunk = l & 7;                     // 4-col chunk

  auto load_af = [&](uint4* dst, int mtv) {
#pragma unroll
    for (int kk = 0; kk < 8; kk++)
      dst[kk] = ap[(size_t)(mtv * 8 + kk) * 64 + l];
  };

  auto body = [&](const uint4* af, int mt) {
    f32x4 acc0 = {0.f, 0.f, 0.f, 0.f}, acc1 = {0.f, 0.f, 0.f, 0.f};
#pragma unroll
    for (int kk = 0; kk < 8; kk++) {
      acc0 = __builtin_amdgcn_mfma_f32_16x16x32_f16(
          __builtin_bit_cast(half8, af[kk]), __builtin_bit_cast(half8, bf0[kk]),
          acc0, 0, 0, 0);
      acc1 = __builtin_amdgcn_mfma_f32_16x16x32_f16(
          __builtin_bit_cast(half8, af[kk]), __builtin_bit_cast(half8, bf1[kk]),
          acc1, 0, 0, 0);
    }
    // wave-private transpose bounce (no barrier; DS in-order per wave)
#pragma unroll
    for (int j = 0; j < 4; j++) {
      otw[(g4 * 4 + j) * 36 + r] = acc0[j];
      otw[(g4 * 4 + j) * 36 + 16 + r] = acc1[j];
    }
    const f32x4 onev = {1.f, 1.f, 1.f, 1.f};
    // fused store (logits + labels) + stats: 8 rows x 32 cols per iter
#pragma unroll
    for (int i = 0; i < 2; i++) {
      int row8 = i * 8 + rlane;
      f32x4 v = *(const f32x4*)&otw[row8 * 36 + cchunk * 4];
      size_t o = (size_t)(mt * 16 + row8) * LCOLS + 3 + nbase + w * 32 + cchunk * 4;
      *(f32x4u*)(out + o) = v * inv_t;
      *(f32x4u*)(out + OFF_LABELS + o) = onev;
      // stats for row8 over this wave's 32 cols (8 lanes x 4 cols)
      float pm = posmin[mt * 16 + row8];
      float s = v.x + v.y + v.z + v.w;
      float s2 = v.x * v.x + v.y * v.y + v.z * v.z + v.w * v.w;
      float mx = fmaxf(fmaxf(v.x, v.y), fmaxf(v.z, v.w));
      float c = (v.x > pm ? 1.f : 0.f) + (v.y > pm ? 1.f : 0.f) +
                (v.z > pm ? 1.f : 0.f) + (v.w > pm ? 1.f : 0.f);
#pragma unroll
      for (int m2 = 1; m2 < 8; m2 <<= 1) {
        s += __shfl_xor(s, m2, 64);
        s2 += __shfl_xor(s2, m2, 64);
        c += __shfl_xor(c, m2, 64);
        mx = fmaxf(mx, __shfl_xor(mx, m2, 64));
      }
      if (cchunk == 0) {
        us4 p = {f2bf(s), f2bf(s2), f2bf(mx), f2bf(c)};
        // [group][row]: 8 lanes write 64B contiguous
        *(us4*)&partials[((size_t)(blk * 4 + w) * 512 + mt * 16 + row8) * 4] = p;
      }
    }
  };

  uint4 afA[8], afB[8];
  load_af(afA, 0);
#pragma unroll 1
  for (int mt2 = 0; mt2 < 16; mt2++) {
    int mt = mt2 * 2;
    load_af(afB, mt + 1);
    body(afA, mt);
    if (mt2 < 15) load_af(afA, mt + 2);
    body(afB, mt + 1);
  }
}

// combine 2048 bf16 partials per row -> score[:, 0:4]. 64 blocks x 8 rows.
__global__ __launch_bounds__(256) void kreduce(const unsigned short* __restrict__ partials,
                                               const float* __restrict__ spos,
                                               float* __restrict__ out) {
  int r0 = blockIdx.x * 8;
  int tid = threadIdx.x;
  float s[8], s2[8], mx[8], c[8];
#pragma unroll
  for (int j = 0; j < 8; j++) { s[j] = 0.f; s2[j] = 0.f; mx[j] = -2.f; c[j] = 0.f; }
  for (int g = tid; g < 2048; g += 256) {
    const unsigned short* pg = partials + ((size_t)g * 512 + r0) * 4;
#pragma unroll
    for (int j = 0; j < 8; j++) {
      us4 v = *(const us4*)(pg + j * 4);
      s[j] += bf2f(v.x); s2[j] += bf2f(v.y);
      mx[j] = fmaxf(mx[j], bf2f(v.z)); c[j] += bf2f(v.w);
    }
  }
#pragma unroll
  for (int j = 0; j < 8; j++) {
#pragma unroll
    for (int m = 1; m < 64; m <<= 1) {
      s[j] += __shfl_xor(s[j], m, 64);
      s2[j] += __shfl_xor(s2[j], m, 64);
      c[j] += __shfl_xor(c[j], m, 64);
      mx[j] = fmaxf(mx[j], __shfl_xor(mx[j], m, 64));
    }
  }
  __shared__ float red[4][8][4];
  int w = tid >> 6, l = tid & 63;
  if (l == 0) {
#pragma unroll
    for (int j = 0; j < 8; j++) {
      red[w][j][0] = s[j]; red[w][j][1] = s2[j];
      red[w][j][2] = c[j]; red[w][j][3] = mx[j];
    }
  }
  __syncthreads();
  if (tid < 8) {
    int row = r0 + tid;
    float S = 0.f, S2 = 0.f, C = 0.f, M = -2.f;
#pragma unroll
    for (int w2 = 0; w2 < 4; w2++) {
      S += red[w2][tid][0]; S2 += red[w2][tid][1];
      C += red[w2][tid][2]; M = fmaxf(M, red[w2][tid][3]);
    }
    float mean = S / (float)NKQ;
    float var = (S2 - S * S / (float)NKQ) / (float)(NKQ - 1);  // ddof=1
    float cp = 0.f;
#pragma unroll
    for (int j = 0; j < 3; j++) cp += (M > spos[row * 3 + j]) ? 1.f : 0.f;
    float* scr = out + OFF_SCORE + (size_t)row * 7;
    scr[0] = mean; scr[1] = var; scr[2] = C; scr[3] = cp;
  }
}

extern "C" void kernel_launch(void* const* d_in, const int* in_sizes, int n_in,
                              void* d_out, int out_size, void* d_ws, size_t ws_size,
                              hipStream_t stream) {
  const float* query = (const float*)d_in[0];
  const float* key_emb = (const float*)d_in[1];
  const float* queue = (const float*)d_in[2];
  float* out = (float*)d_out;
  _Float16* qfrag = (_Float16*)d_ws;
  float* qf32 = (float*)((char*)d_ws + 262144);
  float* posmin = (float*)((char*)d_ws + 786432);
  float* spos = (float*)((char*)d_ws + 788480);
  unsigned short* partials = (unsigned short*)((char*)d_ws + 1048576);

  kprep<<<512, 256, 0, stream>>>(query, key_emb, out, qfrag, qf32);
  kpos<<<512, 64, 0, stream>>>(qf32, out, posmin, spos);
  kgemm<<<512, 256, 0, stream>>>(queue, qfrag, posmin, out, partials);
  kreduce<<<64, 256, 0, stream>>>(partials, spos, out);
}

// Round 12
// 98.295 us; speedup vs baseline: 1.3563x; 1.3563x over previous
//
#include <hip/hip_runtime.h>

#define NB 512
#define ND 256
#define NKQ 65536
#define LCOLS 65539            // 3 + 65536
#define QTAIL 64000            // 65536 - 1536
#define TEMP 0.07f

// d_out element offsets (f32)
#define OFF_LABELS 33555968ull // 512*65539
#define OFF_SCORE  67111936ull // 2*512*65539
#define OFF_QUEUE  67115520ull // OFF_SCORE + 512*7

typedef __attribute__((ext_vector_type(8))) _Float16 half8;
typedef __attribute__((ext_vector_type(4))) float f32x4;
typedef __attribute__((ext_vector_type(4))) unsigned short us4;

__device__ inline float wave_sum(float v) {
#pragma unroll
  for (int m = 1; m < 64; m <<= 1) v += __shfl_xor(v, m, 64);
  return v;
}
__device__ inline unsigned short f2bf(float x) {  // RNE f32->bf16
  union { float f; unsigned u; } v; v.f = x;
  unsigned r = (v.u + 0x7FFF + ((v.u >> 16) & 1)) >> 16;
  return (unsigned short)r;
}
__device__ inline float bf2f(unsigned short h) {
  union { unsigned u; float f; } v; v.u = ((unsigned)h) << 16;
  return v.f;
}

// ws layout (bytes):
// [0, 262144)          : fp16 normalized q in MFMA FRAGMENT ORDER
// [262144, 786432)     : f32 normalized q (row-major, for kpos)
// [786432, 788480)     : pos_min[512]
// [788480, 794624)     : score_pos[512*3]
// [1048576, 9437184)   : stat partials bf16x4 [2048 groups][512 rows]

// 512 blocks: normalize 4 rows each (query -> qfrag/qf32, key -> queue tail)
__global__ __launch_bounds__(256) void kprep(const float* __restrict__ query,
                                             const float* __restrict__ key_emb,
                                             float* __restrict__ out,
                                             _Float16* __restrict__ qfrag,
                                             float* __restrict__ qf32) {
  int blk = blockIdx.x;
  int w = threadIdx.x >> 6, l = threadIdx.x & 63;
  int r = blk * 4 + w;  // 0..2047
  const float* src = (r < NB) ? (query + (size_t)r * ND)
                              : (key_emb + (size_t)(r - NB) * ND);
  float x0 = src[l], x1 = src[l + 64], x2 = src[l + 128], x3 = src[l + 192];
  float ss = wave_sum(x0 * x0 + x1 * x1 + x2 * x2 + x3 * x3);
  float sc = 1.0f / fmaxf(sqrtf(ss), 1e-12f);
  x0 *= sc; x1 *= sc; x2 *= sc; x3 *= sc;
  if (r < NB) {
    float xs[4] = {x0, x1, x2, x3};
    int mt = r >> 4, rr = r & 15;
#pragma unroll
    for (int i = 0; i < 4; i++) {
      int d = l + i * 64;
      qf32[r * ND + d] = xs[i];
      int kk = d >> 5, g4 = (d >> 3) & 3, j = d & 7;
      qfrag[((size_t)(mt * 8 + kk) * 64 + g4 * 16 + rr) * 8 + j] = (_Float16)xs[i];
    }
  } else {
    float* dst = out + OFF_QUEUE + (size_t)(QTAIL + r - NB) * ND;
    dst[l] = x0; dst[l + 64] = x1; dst[l + 128] = x2; dst[l + 192] = x3;
  }
}

__global__ __launch_bounds__(64) void kpos(const float* __restrict__ qf32,
                                           float* __restrict__ out,
                                           float* __restrict__ posmin,
                                           float* __restrict__ spos) {
  int b = blockIdx.x, l = threadIdx.x;
  const float* q = qf32 + (size_t)b * ND;
  float q0 = q[l], q1 = q[l + 64], q2 = q[l + 128], q3 = q[l + 192];
  const float* kbase = out + OFF_QUEUE + (size_t)(QTAIL + b * 3) * ND;
  float sp[3];
#pragma unroll
  for (int j = 0; j < 3; j++) {
    const float* kp = kbase + (size_t)j * ND;
    float p = q0 * kp[l] + q1 * kp[l + 64] + q2 * kp[l + 128] + q3 * kp[l + 192];
    sp[j] = wave_sum(p);
  }
  if (l == 0) {
    float* lg = out + (size_t)b * LCOLS;
    float* scr = out + OFF_SCORE + (size_t)b * 7;
#pragma unroll
    for (int j = 0; j < 3; j++) {
      lg[j] = sp[j] / TEMP;
      scr[4 + j] = sp[j];
      spos[b * 3 + j] = sp[j];
    }
    posmin[b] = fminf(sp[0], fminf(sp[1], sp[2]));
  }
}

// Round-10 kgemm (best known) + co-resident labels-fill blocks.
// Blocks 0..511: GEMM over 128 cols each (verbatim r10 internals).
// Blocks 512..895: grid-stride nontemporal fill of the labels region —
// overlaps the GEMM blocks' latency/compute phases on other CUs.
__global__ __launch_bounds__(256) void kgemm(const float* __restrict__ queue,
                                             const _Float16* __restrict__ qfrag,
                                             const float* __restrict__ posmin,
                                             float* __restrict__ out,
                                             unsigned short* __restrict__ partials) {
  __shared__ __align__(16) float ot[4][16 * 36];  // per-wave private regions
  int tid = threadIdx.x;
  if ((int)blockIdx.x >= 512) {
    // labels = ones over the whole [512][65539] region, flat f32x4 fill
    f32x4 one = {1.f, 1.f, 1.f, 1.f};
    f32x4* lb = (f32x4*)(out + OFF_LABELS);
    const long total4 = (long)NB * LCOLS / 4;  // 8388992, exact
    long stride = (long)384 * 256;
    for (long i = (long)((int)blockIdx.x - 512) * 256 + tid; i < total4;
         i += stride)
      __builtin_nontemporal_store(one, lb + i);
    return;
  }
  // XCD swizzle: adjacent column-blocks share an XCD L2 (512 % 8 == 0)
  int blk = ((int)blockIdx.x & 7) * 64 + ((int)blockIdx.x >> 3);
  int nbase = blk * 128;
  int w = tid >> 6, l = tid & 63;
  int r = l & 15, g4 = l >> 4;
  float* otw = ot[w];

  // Phase 0: fused FIFO copy of this block's 128 queue rows (warms L2)
  const f32x4* qp = (const f32x4*)queue;
  f32x4* nq = (f32x4*)(out + OFF_QUEUE);
#pragma unroll
  for (int i = 0; i < 32; i++) {
    int idx = tid + i * 256;          // 128 rows * 64 f32x4
    int row = idx >> 6, c4 = idx & 63;
    int grow = nbase + row;
    f32x4 v = qp[(size_t)grow * 64 + c4];
    if (grow >= 1536)
      __builtin_nontemporal_store(v, nq + (size_t)(grow - 1536) * 64 + c4);
  }

  // Phase 1: per-wave B fragments in registers (32 cols per wave, one-time)
  uint4 bf0[8], bf1[8];
  {
    const float* qrow0 = queue + (size_t)(nbase + w * 32 + r) * ND;
    const float* qrow1 = qrow0 + 16 * ND;
#pragma unroll
    for (int kk = 0; kk < 8; kk++) {
      int k0 = kk * 32 + g4 * 8;
      f32x4 a0 = *(const f32x4*)(qrow0 + k0);
      f32x4 a1 = *(const f32x4*)(qrow0 + k0 + 4);
      f32x4 b0 = *(const f32x4*)(qrow1 + k0);
      f32x4 b1 = *(const f32x4*)(qrow1 + k0 + 4);
      half8 h0, h1;
      h0[0] = (_Float16)a0.x; h0[1] = (_Float16)a0.y; h0[2] = (_Float16)a0.z;
      h0[3] = (_Float16)a0.w; h0[4] = (_Float16)a1.x; h0[5] = (_Float16)a1.y;
      h0[6] = (_Float16)a1.z; h0[7] = (_Float16)a1.w;
      h1[0] = (_Float16)b0.x; h1[1] = (_Float16)b0.y; h1[2] = (_Float16)b0.z;
      h1[3] = (_Float16)b0.w; h1[4] = (_Float16)b1.x; h1[5] = (_Float16)b1.y;
      h1[6] = (_Float16)b1.z; h1[7] = (_Float16)b1.w;
      bf0[kk] = __builtin_bit_cast(uint4, h0);
      bf1[kk] = __builtin_bit_cast(uint4, h1);
    }
  }

  const uint4* ap = (const uint4*)qfrag;  // COALESCED: idx = (mt*8+kk)*64 + l
  const float inv_t = 1.0f / TEMP;
  int rr = l >> 2, qq = l & 3;           // stats: 4 lanes per row

  auto load_af = [&](uint4* dst, int mtv) {
#pragma unroll
    for (int kk = 0; kk < 8; kk++)
      dst[kk] = ap[(size_t)(mtv * 8 + kk) * 64 + l];
  };

  auto body = [&](const uint4* af, int mt) {
    f32x4 acc0 = {0.f, 0.f, 0.f, 0.f}, acc1 = {0.f, 0.f, 0.f, 0.f};
#pragma unroll
    for (int kk = 0; kk < 8; kk++) {
      acc0 = __builtin_amdgcn_mfma_f32_16x16x32_f16(
          __builtin_bit_cast(half8, af[kk]), __builtin_bit_cast(half8, bf0[kk]),
          acc0, 0, 0, 0);
      acc1 = __builtin_amdgcn_mfma_f32_16x16x32_f16(
          __builtin_bit_cast(half8, af[kk]), __builtin_bit_cast(half8, bf1[kk]),
          acc1, 0, 0, 0);
    }
    // wave-private transpose bounce (no barrier; DS is in-order per wave)
#pragma unroll
    for (int j = 0; j < 4; j++) {
      otw[(g4 * 4 + j) * 36 + r] = acc0[j];
      otw[(g4 * 4 + j) * 36 + 16 + r] = acc1[j];
    }
    // logits: scalar dword stores, 2 rows x 32 cols per instr (coalesces clean)
#pragma unroll
    for (int i = 0; i < 8; i++) {
      int row2 = i * 2 + (l >> 5), col = l & 31;
      float v = otw[row2 * 36 + col];
      out[(size_t)(mt * 16 + row2) * LCOLS + 3 + nbase + w * 32 + col] =
          v * inv_t;
    }
    // stats: lane covers 8 cols of row rr; reduce over 4-lane group
    f32x4 s0 = *(const f32x4*)&otw[rr * 36 + qq * 8];
    f32x4 s1 = *(const f32x4*)&otw[rr * 36 + qq * 8 + 4];
    float pm = posmin[mt * 16 + rr];
    float s = s0.x + s0.y + s0.z + s0.w + s1.x + s1.y + s1.z + s1.w;
    float s2 = s0.x * s0.x + s0.y * s0.y + s0.z * s0.z + s0.w * s0.w +
               s1.x * s1.x + s1.y * s1.y + s1.z * s1.z + s1.w * s1.w;
    float mx = fmaxf(fmaxf(fmaxf(s0.x, s0.y), fmaxf(s0.z, s0.w)),
                     fmaxf(fmaxf(s1.x, s1.y), fmaxf(s1.z, s1.w)));
    float c = (s0.x > pm ? 1.f : 0.f) + (s0.y > pm ? 1.f : 0.f) +
              (s0.z > pm ? 1.f : 0.f) + (s0.w > pm ? 1.f : 0.f) +
              (s1.x > pm ? 1.f : 0.f) + (s1.y > pm ? 1.f : 0.f) +
              (s1.z > pm ? 1.f : 0.f) + (s1.w > pm ? 1.f : 0.f);
#pragma unroll
    for (int m = 1; m < 4; m <<= 1) {
      s += __shfl_xor(s, m, 64);
      s2 += __shfl_xor(s2, m, 64);
      c += __shfl_xor(c, m, 64);
      mx = fmaxf(mx, __shfl_xor(mx, m, 64));
    }
    if (qq == 0) {
      us4 p = {f2bf(s), f2bf(s2), f2bf(mx), f2bf(c)};
      // [group][row]: 16 lanes/wave write 128B contiguous
      *(us4*)&partials[((size_t)(blk * 4 + w) * 512 + mt * 16 + rr) * 4] = p;
    }
  };

  uint4 afA[8], afB[8];
  load_af(afA, 0);
#pragma unroll 1
  for (int mt2 = 0; mt2 < 16; mt2++) {
    int mt = mt2 * 2;
    load_af(afB, mt + 1);
    body(afA, mt);
    if (mt2 < 15) load_af(afA, mt + 2);
    body(afB, mt + 1);
  }
}

// combine 2048 bf16 partials per row -> score[:, 0:4]. 64 blocks x 8 rows.
__global__ __launch_bounds__(256) void kreduce(const unsigned short* __restrict__ partials,
                                               const float* __restrict__ spos,
                                               float* __restrict__ out) {
  int r0 = blockIdx.x * 8;
  int tid = threadIdx.x;
  float s[8], s2[8], mx[8], c[8];
#pragma unroll
  for (int j = 0; j < 8; j++) { s[j] = 0.f; s2[j] = 0.f; mx[j] = -2.f; c[j] = 0.f; }
  for (int g = tid; g < 2048; g += 256) {
    const unsigned short* pg = partials + ((size_t)g * 512 + r0) * 4;
#pragma unroll
    for (int j = 0; j < 8; j++) {
      us4 v = *(const us4*)(pg + j * 4);
      s[j] += bf2f(v.x); s2[j] += bf2f(v.y);
      mx[j] = fmaxf(mx[j], bf2f(v.z)); c[j] += bf2f(v.w);
    }
  }
#pragma unroll
  for (int j = 0; j < 8; j++) {
#pragma unroll
    for (int m = 1; m < 64; m <<= 1) {
      s[j] += __shfl_xor(s[j], m, 64);
      s2[j] += __shfl_xor(s2[j], m, 64);
      c[j] += __shfl_xor(c[j], m, 64);
      mx[j] = fmaxf(mx[j], __shfl_xor(mx[j], m, 64));
    }
  }
  __shared__ float red[4][8][4];
  int w = tid >> 6, l = tid & 63;
  if (l == 0) {
#pragma unroll
    for (int j = 0; j < 8; j++) {
      red[w][j][0] = s[j]; red[w][j][1] = s2[j];
      red[w][j][2] = c[j]; red[w][j][3] = mx[j];
    }
  }
  __syncthreads();
  if (tid < 8) {
    int row = r0 + tid;
    float S = 0.f, S2 = 0.f, C = 0.f, M = -2.f;
#pragma unroll
    for (int w2 = 0; w2 < 4; w2++) {
      S += red[w2][tid][0]; S2 += red[w2][tid][1];
      C += red[w2][tid][2]; M = fmaxf(M, red[w2][tid][3]);
    }
    float mean = S / (float)NKQ;
    float var = (S2 - S * S / (float)NKQ) / (float)(NKQ - 1);  // ddof=1
    float cp = 0.f;
#pragma unroll
    for (int j = 0; j < 3; j++) cp += (M > spos[row * 3 + j]) ? 1.f : 0.f;
    float* scr = out + OFF_SCORE + (size_t)row * 7;
    scr[0] = mean; scr[1] = var; scr[2] = C; scr[3] = cp;
  }
}

extern "C" void kernel_launch(void* const* d_in, const int* in_sizes, int n_in,
                              void* d_out, int out_size, void* d_ws, size_t ws_size,
                              hipStream_t stream) {
  const float* query = (const float*)d_in[0];
  const float* key_emb = (const float*)d_in[1];
  const float* queue = (const float*)d_in[2];
  float* out = (float*)d_out;
  _Float16* qfrag = (_Float16*)d_ws;
  float* qf32 = (float*)((char*)d_ws + 262144);
  float* posmin = (float*)((char*)d_ws + 786432);
  float* spos = (float*)((char*)d_ws + 788480);
  unsigned short* partials = (unsigned short*)((char*)d_ws + 1048576);

  kprep<<<512, 256, 0, stream>>>(query, key_emb, out, qfrag, qf32);
  kpos<<<512, 64, 0, stream>>>(qf32, out, posmin, spos);
  kgemm<<<896, 256, 0, stream>>>(queue, qfrag, posmin, out, partials);
  kreduce<<<64, 256, 0, stream>>>(partials, spos, out);
}

// Round 13
// 95.598 us; speedup vs baseline: 1.3945x; 1.0282x over previous
//
#include <hip/hip_runtime.h>

#define NB 512
#define ND 256
#define NKQ 65536
#define LCOLS 65539            // 3 + 65536
#define QTAIL 64000            // 65536 - 1536
#define TEMP 0.07f

// d_out element offsets (f32)
#define OFF_LABELS 33555968ull // 512*65539
#define OFF_SCORE  67111936ull // 2*512*65539
#define OFF_QUEUE  67115520ull // OFF_SCORE + 512*7

typedef __attribute__((ext_vector_type(8))) _Float16 half8;
typedef __attribute__((ext_vector_type(4))) float f32x4;
typedef __attribute__((ext_vector_type(4))) unsigned short us4;

__device__ inline float wave_sum(float v) {
#pragma unroll
  for (int m = 1; m < 64; m <<= 1) v += __shfl_xor(v, m, 64);
  return v;
}
__device__ inline unsigned short f2bf(float x) {  // RNE f32->bf16
  union { float f; unsigned u; } v; v.f = x;
  unsigned r = (v.u + 0x7FFF + ((v.u >> 16) & 1)) >> 16;
  return (unsigned short)r;
}
__device__ inline float bf2f(unsigned short h) {
  union { unsigned u; float f; } v; v.u = ((unsigned)h) << 16;
  return v.f;
}

// ws layout (bytes):
// [0, 262144)          : fp16 normalized q in MFMA FRAGMENT ORDER
// [786432, 788480)     : pos_min[512]
// [788480, 794624)     : score_pos[512*3]
// [1048576, 9437184)   : stat partials bf16x4 [2048 groups][512 rows]

// Fused prep+pos, 1024 blocks:
// blocks 0..511   : normalize 4 rows each (query -> qfrag, key -> queue tail)
// blocks 512..1023: block 512+b computes the 3 positive dots for q-row b,
//                   renormalizing q[b] and key rows 3b..3b+2 locally from the
//                   raw inputs (identical f32 expressions -> same results).
__global__ __launch_bounds__(256) void kfused(const float* __restrict__ query,
                                              const float* __restrict__ key_emb,
                                              float* __restrict__ out,
                                              _Float16* __restrict__ qfrag,
                                              float* __restrict__ posmin,
                                              float* __restrict__ spos) {
  int blk = blockIdx.x;
  int w = threadIdx.x >> 6, l = threadIdx.x & 63;
  if (blk < 512) {
    int r = blk * 4 + w;  // 0..2047
    const float* src = (r < NB) ? (query + (size_t)r * ND)
                                : (key_emb + (size_t)(r - NB) * ND);
    float x0 = src[l], x1 = src[l + 64], x2 = src[l + 128], x3 = src[l + 192];
    float ss = wave_sum(x0 * x0 + x1 * x1 + x2 * x2 + x3 * x3);
    float sc = 1.0f / fmaxf(sqrtf(ss), 1e-12f);
    x0 *= sc; x1 *= sc; x2 *= sc; x3 *= sc;
    if (r < NB) {
      float xs[4] = {x0, x1, x2, x3};
      int mt = r >> 4, rr = r & 15;
#pragma unroll
      for (int i = 0; i < 4; i++) {
        int d = l + i * 64;
        int kk = d >> 5, g4 = (d >> 3) & 3, j = d & 7;
        qfrag[((size_t)(mt * 8 + kk) * 64 + g4 * 16 + rr) * 8 + j] =
            (_Float16)xs[i];
      }
    } else {
      float* dst = out + OFF_QUEUE + (size_t)(QTAIL + r - NB) * ND;
      dst[l] = x0; dst[l + 64] = x1; dst[l + 128] = x2; dst[l + 192] = x3;
    }
  } else {
    int b = blk - 512;  // q row
    __shared__ float qsh[256];
    __shared__ float sps[3];
    const float* src = (w == 0) ? query + (size_t)b * ND
                                : key_emb + (size_t)(3 * b + w - 1) * ND;
    float x0 = src[l], x1 = src[l + 64], x2 = src[l + 128], x3 = src[l + 192];
    float ss = wave_sum(x0 * x0 + x1 * x1 + x2 * x2 + x3 * x3);
    float sc = 1.0f / fmaxf(sqrtf(ss), 1e-12f);
    x0 *= sc; x1 *= sc; x2 *= sc; x3 *= sc;
    if (w == 0) {
      qsh[l] = x0; qsh[l + 64] = x1; qsh[l + 128] = x2; qsh[l + 192] = x3;
    }
    __syncthreads();
    if (w > 0) {
      float d = x0 * qsh[l] + x1 * qsh[l + 64] + x2 * qsh[l + 128] +
                x3 * qsh[l + 192];
      d = wave_sum(d);
      if (l == 0) sps[w - 1] = d;
    }
    __syncthreads();
    if (threadIdx.x == 0) {
      float s0 = sps[0], s1 = sps[1], s2 = sps[2];
      float* lg = out + (size_t)b * LCOLS;
      float* scr = out + OFF_SCORE + (size_t)b * 7;
      lg[0] = s0 / TEMP; lg[1] = s1 / TEMP; lg[2] = s2 / TEMP;
      scr[4] = s0; scr[5] = s1; scr[6] = s2;
      spos[b * 3 + 0] = s0; spos[b * 3 + 1] = s1; spos[b * 3 + 2] = s2;
      posmin[b] = fminf(s0, fminf(s1, s2));
    }
  }
}

// Round-12 kgemm verbatim (best known: coalesced qfrag loads, wave-private
// otile, scalar-dword logits stores, co-resident labels-fill blocks).
__global__ __launch_bounds__(256) void kgemm(const float* __restrict__ queue,
                                             const _Float16* __restrict__ qfrag,
                                             const float* __restrict__ posmin,
                                             float* __restrict__ out,
                                             unsigned short* __restrict__ partials) {
  __shared__ __align__(16) float ot[4][16 * 36];  // per-wave private regions
  int tid = threadIdx.x;
  if ((int)blockIdx.x >= 512) {
    // labels = ones over the whole [512][65539] region, flat f32x4 fill
    f32x4 one = {1.f, 1.f, 1.f, 1.f};
    f32x4* lb = (f32x4*)(out + OFF_LABELS);
    const long total4 = (long)NB * LCOLS / 4;  // 8388992, exact
    long stride = (long)384 * 256;
    for (long i = (long)((int)blockIdx.x - 512) * 256 + tid; i < total4;
         i += stride)
      __builtin_nontemporal_store(one, lb + i);
    return;
  }
  // XCD swizzle: adjacent column-blocks share an XCD L2 (512 % 8 == 0)
  int blk = ((int)blockIdx.x & 7) * 64 + ((int)blockIdx.x >> 3);
  int nbase = blk * 128;
  int w = tid >> 6, l = tid & 63;
  int r = l & 15, g4 = l >> 4;
  float* otw = ot[w];

  // Phase 0: fused FIFO copy of this block's 128 queue rows (warms L2)
  const f32x4* qp = (const f32x4*)queue;
  f32x4* nq = (f32x4*)(out + OFF_QUEUE);
#pragma unroll
  for (int i = 0; i < 32; i++) {
    int idx = tid + i * 256;          // 128 rows * 64 f32x4
    int row = idx >> 6, c4 = idx & 63;
    int grow = nbase + row;
    f32x4 v = qp[(size_t)grow * 64 + c4];
    if (grow >= 1536)
      __builtin_nontemporal_store(v, nq + (size_t)(grow - 1536) * 64 + c4);
  }

  // Phase 1: per-wave B fragments in registers (32 cols per wave, one-time)
  uint4 bf0[8], bf1[8];
  {
    const float* qrow0 = queue + (size_t)(nbase + w * 32 + r) * ND;
    const float* qrow1 = qrow0 + 16 * ND;
#pragma unroll
    for (int kk = 0; kk < 8; kk++) {
      int k0 = kk * 32 + g4 * 8;
      f32x4 a0 = *(const f32x4*)(qrow0 + k0);
      f32x4 a1 = *(const f32x4*)(qrow0 + k0 + 4);
      f32x4 b0 = *(const f32x4*)(qrow1 + k0);
      f32x4 b1 = *(const f32x4*)(qrow1 + k0 + 4);
      half8 h0, h1;
      h0[0] = (_Float16)a0.x; h0[1] = (_Float16)a0.y; h0[2] = (_Float16)a0.z;
      h0[3] = (_Float16)a0.w; h0[4] = (_Float16)a1.x; h0[5] = (_Float16)a1.y;
      h0[6] = (_Float16)a1.z; h0[7] = (_Float16)a1.w;
      h1[0] = (_Float16)b0.x; h1[1] = (_Float16)b0.y; h1[2] = (_Float16)b0.z;
      h1[3] = (_Float16)b0.w; h1[4] = (_Float16)b1.x; h1[5] = (_Float16)b1.y;
      h1[6] = (_Float16)b1.z; h1[7] = (_Float16)b1.w;
      bf0[kk] = __builtin_bit_cast(uint4, h0);
      bf1[kk] = __builtin_bit_cast(uint4, h1);
    }
  }

  const uint4* ap = (const uint4*)qfrag;  // COALESCED: idx = (mt*8+kk)*64 + l
  const float inv_t = 1.0f / TEMP;
  int rr = l >> 2, qq = l & 3;           // stats: 4 lanes per row

  auto load_af = [&](uint4* dst, int mtv) {
#pragma unroll
    for (int kk = 0; kk < 8; kk++)
      dst[kk] = ap[(size_t)(mtv * 8 + kk) * 64 + l];
  };

  auto body = [&](const uint4* af, int mt) {
    f32x4 acc0 = {0.f, 0.f, 0.f, 0.f}, acc1 = {0.f, 0.f, 0.f, 0.f};
#pragma unroll
    for (int kk = 0; kk < 8; kk++) {
      acc0 = __builtin_amdgcn_mfma_f32_16x16x32_f16(
          __builtin_bit_cast(half8, af[kk]), __builtin_bit_cast(half8, bf0[kk]),
          acc0, 0, 0, 0);
      acc1 = __builtin_amdgcn_mfma_f32_16x16x32_f16(
          __builtin_bit_cast(half8, af[kk]), __builtin_bit_cast(half8, bf1[kk]),
          acc1, 0, 0, 0);
    }
    // wave-private transpose bounce (no barrier; DS is in-order per wave)
#pragma unroll
    for (int j = 0; j < 4; j++) {
      otw[(g4 * 4 + j) * 36 + r] = acc0[j];
      otw[(g4 * 4 + j) * 36 + 16 + r] = acc1[j];
    }
    // logits: scalar dword stores, 2 rows x 32 cols per instr (coalesces clean)
#pragma unroll
    for (int i = 0; i < 8; i++) {
      int row2 = i * 2 + (l >> 5), col = l & 31;
      float v = otw[row2 * 36 + col];
      out[(size_t)(mt * 16 + row2) * LCOLS + 3 + nbase + w * 32 + col] =
          v * inv_t;
    }
    // stats: lane covers 8 cols of row rr; reduce over 4-lane group
    f32x4 s0 = *(const f32x4*)&otw[rr * 36 + qq * 8];
    f32x4 s1 = *(const f32x4*)&otw[rr * 36 + qq * 8 + 4];
    float pm = posmin[mt * 16 + rr];
    float s = s0.x + s0.y + s0.z + s0.w + s1.x + s1.y + s1.z + s1.w;
    float s2 = s0.x * s0.x + s0.y * s0.y + s0.z * s0.z + s0.w * s0.w +
               s1.x * s1.x + s1.y * s1.y + s1.z * s1.z + s1.w * s1.w;
    float mx = fmaxf(fmaxf(fmaxf(s0.x, s0.y), fmaxf(s0.z, s0.w)),
                     fmaxf(fmaxf(s1.x, s1.y), fmaxf(s1.z, s1.w)));
    float c = (s0.x > pm ? 1.f : 0.f) + (s0.y > pm ? 1.f : 0.f) +
              (s0.z > pm ? 1.f : 0.f) + (s0.w > pm ? 1.f : 0.f) +
              (s1.x > pm ? 1.f : 0.f) + (s1.y > pm ? 1.f : 0.f) +
              (s1.z > pm ? 1.f : 0.f) + (s1.w > pm ? 1.f : 0.f);
#pragma unroll
    for (int m = 1; m < 4; m <<= 1) {
      s += __shfl_xor(s, m, 64);
      s2 += __shfl_xor(s2, m, 64);
      c += __shfl_xor(c, m, 64);
      mx = fmaxf(mx, __shfl_xor(mx, m, 64));
    }
    if (qq == 0) {
      us4 p = {f2bf(s), f2bf(s2), f2bf(mx), f2bf(c)};
      // [group][row]: 16 lanes/wave write 128B contiguous
      *(us4*)&partials[((size_t)(blk * 4 + w) * 512 + mt * 16 + rr) * 4] = p;
    }
  };

  uint4 afA[8], afB[8];
  load_af(afA, 0);
#pragma unroll 1
  for (int mt2 = 0; mt2 < 16; mt2++) {
    int mt = mt2 * 2;
    load_af(afB, mt + 1);
    body(afA, mt);
    if (mt2 < 15) load_af(afA, mt + 2);
    body(afB, mt + 1);
  }
}

// combine 2048 bf16 partials per row -> score[:, 0:4]. 64 blocks x 8 rows.
__global__ __launch_bounds__(256) void kreduce(const unsigned short* __restrict__ partials,
                                               const float* __restrict__ spos,
                                               float* __restrict__ out) {
  int r0 = blockIdx.x * 8;
  int tid = threadIdx.x;
  float s[8], s2[8], mx[8], c[8];
#pragma unroll
  for (int j = 0; j < 8; j++) { s[j] = 0.f; s2[j] = 0.f; mx[j] = -2.f; c[j] = 0.f; }
  for (int g = tid; g < 2048; g += 256) {
    const unsigned short* pg = partials + ((size_t)g * 512 + r0) * 4;
#pragma unroll
    for (int j = 0; j < 8; j++) {
      us4 v = *(const us4*)(pg + j * 4);
      s[j] += bf2f(v.x); s2[j] += bf2f(v.y);
      mx[j] = fmaxf(mx[j], bf2f(v.z)); c[j] += bf2f(v.w);
    }
  }
#pragma unroll
  for (int j = 0; j < 8; j++) {
#pragma unroll
    for (int m = 1; m < 64; m <<= 1) {
      s[j] += __shfl_xor(s[j], m, 64);
      s2[j] += __shfl_xor(s2[j], m, 64);
      c[j] += __shfl_xor(c[j], m, 64);
      mx[j] = fmaxf(mx[j], __shfl_xor(mx[j], m, 64));
    }
  }
  __shared__ float red[4][8][4];
  int w = tid >> 6, l = tid & 63;
  if (l == 0) {
#pragma unroll
    for (int j = 0; j < 8; j++) {
      red[w][j][0] = s[j]; red[w][j][1] = s2[j];
      red[w][j][2] = c[j]; red[w][j][3] = mx[j];
    }
  }
  __syncthreads();
  if (tid < 8) {
    int row = r0 + tid;
    float S = 0.f, S2 = 0.f, C = 0.f, M = -2.f;
#pragma unroll
    for (int w2 = 0; w2 < 4; w2++) {
      S += red[w2][tid][0]; S2 += red[w2][tid][1];
      C += red[w2][tid][2]; M = fmaxf(M, red[w2][tid][3]);
    }
    float mean = S / (float)NKQ;
    float var = (S2 - S * S / (float)NKQ) / (float)(NKQ - 1);  // ddof=1
    float cp = 0.f;
#pragma unroll
    for (int j = 0; j < 3; j++) cp += (M > spos[row * 3 + j]) ? 1.f : 0.f;
    float* scr = out + OFF_SCORE + (size_t)row * 7;
    scr[0] = mean; scr[1] = var; scr[2] = C; scr[3] = cp;
  }
}

extern "C" void kernel_launch(void* const* d_in, const int* in_sizes, int n_in,
                              void* d_out, int out_size, void* d_ws, size_t ws_size,
                              hipStream_t stream) {
  const float* query = (const float*)d_in[0];
  const float* key_emb = (const float*)d_in[1];
  const float* queue = (const float*)d_in[2];
  float* out = (float*)d_out;
  _Float16* qfrag = (_Float16*)d_ws;
  float* posmin = (float*)((char*)d_ws + 786432);
  float* spos = (float*)((char*)d_ws + 788480);
  unsigned short* partials = (unsigned short*)((char*)d_ws + 1048576);

  kfused<<<1024, 256, 0, stream>>>(query, key_emb, out, qfrag, posmin, spos);
  kgemm<<<896, 256, 0, stream>>>(queue, qfrag, posmin, out, partials);
  kreduce<<<64, 256, 0, stream>>>(partials, spos, out);
}

// Round 14
// 88.245 us; speedup vs baseline: 1.5107x; 1.0833x over previous
//
#include <hip/hip_runtime.h>

#define NB 512
#define ND 256
#define NKQ 65536
#define LCOLS 65539            // 3 + 65536
#define QTAIL 64000            // 65536 - 1536
#define TEMP 0.07f

// d_out element offsets (f32)
#define OFF_LABELS 33555968ull // 512*65539
#define OFF_SCORE  67111936ull // 2*512*65539
#define OFF_QUEUE  67115520ull // OFF_SCORE + 512*7

typedef __attribute__((ext_vector_type(8))) _Float16 half8;
typedef __attribute__((ext_vector_type(4))) float f32x4;
typedef __attribute__((ext_vector_type(4))) unsigned short us4;

__device__ inline float wave_sum(float v) {
#pragma unroll
  for (int m = 1; m < 64; m <<= 1) v += __shfl_xor(v, m, 64);
  return v;
}
__device__ inline unsigned short f2bf(float x) {  // RNE f32->bf16
  union { float f; unsigned u; } v; v.f = x;
  unsigned r = (v.u + 0x7FFF + ((v.u >> 16) & 1)) >> 16;
  return (unsigned short)r;
}
__device__ inline float bf2f(unsigned short h) {
  union { unsigned u; float f; } v; v.u = ((unsigned)h) << 16;
  return v.f;
}

// ws layout (bytes):
// [0, 262144)          : fp16 normalized q in MFMA FRAGMENT ORDER
// [786432, 788480)     : pos_min[512]
// [788480, 794624)     : score_pos[512*3]
// [1048576, 9437184)   : stat partials bf16x4 [2048 groups][512 rows]

// Fused prep+pos, 1024 blocks (verbatim r13).
__global__ __launch_bounds__(256) void kfused(const float* __restrict__ query,
                                              const float* __restrict__ key_emb,
                                              float* __restrict__ out,
                                              _Float16* __restrict__ qfrag,
                                              float* __restrict__ posmin,
                                              float* __restrict__ spos) {
  int blk = blockIdx.x;
  int w = threadIdx.x >> 6, l = threadIdx.x & 63;
  if (blk < 512) {
    int r = blk * 4 + w;  // 0..2047
    const float* src = (r < NB) ? (query + (size_t)r * ND)
                                : (key_emb + (size_t)(r - NB) * ND);
    float x0 = src[l], x1 = src[l + 64], x2 = src[l + 128], x3 = src[l + 192];
    float ss = wave_sum(x0 * x0 + x1 * x1 + x2 * x2 + x3 * x3);
    float sc = 1.0f / fmaxf(sqrtf(ss), 1e-12f);
    x0 *= sc; x1 *= sc; x2 *= sc; x3 *= sc;
    if (r < NB) {
      float xs[4] = {x0, x1, x2, x3};
      int mt = r >> 4, rr = r & 15;
#pragma unroll
      for (int i = 0; i < 4; i++) {
        int d = l + i * 64;
        int kk = d >> 5, g4 = (d >> 3) & 3, j = d & 7;
        qfrag[((size_t)(mt * 8 + kk) * 64 + g4 * 16 + rr) * 8 + j] =
            (_Float16)xs[i];
      }
    } else {
      float* dst = out + OFF_QUEUE + (size_t)(QTAIL + r - NB) * ND;
      dst[l] = x0; dst[l + 64] = x1; dst[l + 128] = x2; dst[l + 192] = x3;
    }
  } else {
    int b = blk - 512;  // q row
    __shared__ float qsh[256];
    __shared__ float sps[3];
    const float* src = (w == 0) ? query + (size_t)b * ND
                                : key_emb + (size_t)(3 * b + w - 1) * ND;
    float x0 = src[l], x1 = src[l + 64], x2 = src[l + 128], x3 = src[l + 192];
    float ss = wave_sum(x0 * x0 + x1 * x1 + x2 * x2 + x3 * x3);
    float sc = 1.0f / fmaxf(sqrtf(ss), 1e-12f);
    x0 *= sc; x1 *= sc; x2 *= sc; x3 *= sc;
    if (w == 0) {
      qsh[l] = x0; qsh[l + 64] = x1; qsh[l + 128] = x2; qsh[l + 192] = x3;
    }
    __syncthreads();
    if (w > 0) {
      float d = x0 * qsh[l] + x1 * qsh[l + 64] + x2 * qsh[l + 128] +
                x3 * qsh[l + 192];
      d = wave_sum(d);
      if (l == 0) sps[w - 1] = d;
    }
    __syncthreads();
    if (threadIdx.x == 0) {
      float s0 = sps[0], s1 = sps[1], s2 = sps[2];
      float* lg = out + (size_t)b * LCOLS;
      float* scr = out + OFF_SCORE + (size_t)b * 7;
      lg[0] = s0 / TEMP; lg[1] = s1 / TEMP; lg[2] = s2 / TEMP;
      scr[4] = s0; scr[5] = s1; scr[6] = s2;
      spos[b * 3 + 0] = s0; spos[b * 3 + 1] = s1; spos[b * 3 + 2] = s2;
      posmin[b] = fminf(s0, fminf(s1, s2));
    }
  }
}

// r13 kgemm with the labels fill INTERLEAVED into each block's main loop
// (2 aligned nontemporal f32x4 stores per body) instead of tail fill blocks.
__global__ __launch_bounds__(256) void kgemm(const float* __restrict__ queue,
                                             const _Float16* __restrict__ qfrag,
                                             const float* __restrict__ posmin,
                                             float* __restrict__ out,
                                             unsigned short* __restrict__ partials) {
  __shared__ __align__(16) float ot[4][16 * 36];  // per-wave private regions
  int tid = threadIdx.x;
  int braw = (int)blockIdx.x;
  // XCD swizzle: adjacent column-blocks share an XCD L2 (512 % 8 == 0)
  int blk = (braw & 7) * 64 + (braw >> 3);
  int nbase = blk * 128;
  int w = tid >> 6, l = tid & 63;
  int r = l & 15, g4 = l >> 4;
  float* otw = ot[w];
  // this block's contiguous labels slice (aligned f32x4)
  f32x4* lbl = (f32x4*)(out + OFF_LABELS) + (size_t)braw * 16384;
  const f32x4 onev = {1.f, 1.f, 1.f, 1.f};

  // Phase 0: fused FIFO copy of this block's 128 queue rows (warms L2)
  const f32x4* qp = (const f32x4*)queue;
  f32x4* nq = (f32x4*)(out + OFF_QUEUE);
#pragma unroll
  for (int i = 0; i < 32; i++) {
    int idx = tid + i * 256;          // 128 rows * 64 f32x4
    int row = idx >> 6, c4 = idx & 63;
    int grow = nbase + row;
    f32x4 v = qp[(size_t)grow * 64 + c4];
    if (grow >= 1536)
      __builtin_nontemporal_store(v, nq + (size_t)(grow - 1536) * 64 + c4);
  }
  // labels remainder: 8388992 - 512*16384 = 384 f32x4, one per block 0..383
  if (braw < 384 && tid == 0)
    __builtin_nontemporal_store(onev,
                                (f32x4*)(out + OFF_LABELS) + 8388608 + braw);

  // Phase 1: per-wave B fragments in registers (32 cols per wave, one-time)
  uint4 bf0[8], bf1[8];
  {
    const float* qrow0 = queue + (size_t)(nbase + w * 32 + r) * ND;
    const float* qrow1 = qrow0 + 16 * ND;
#pragma unroll
    for (int kk = 0; kk < 8; kk++) {
      int k0 = kk * 32 + g4 * 8;
      f32x4 a0 = *(const f32x4*)(qrow0 + k0);
      f32x4 a1 = *(const f32x4*)(qrow0 + k0 + 4);
      f32x4 b0 = *(const f32x4*)(qrow1 + k0);
      f32x4 b1 = *(const f32x4*)(qrow1 + k0 + 4);
      half8 h0, h1;
      h0[0] = (_Float16)a0.x; h0[1] = (_Float16)a0.y; h0[2] = (_Float16)a0.z;
      h0[3] = (_Float16)a0.w; h0[4] = (_Float16)a1.x; h0[5] = (_Float16)a1.y;
      h0[6] = (_Float16)a1.z; h0[7] = (_Float16)a1.w;
      h1[0] = (_Float16)b0.x; h1[1] = (_Float16)b0.y; h1[2] = (_Float16)b0.z;
      h1[3] = (_Float16)b0.w; h1[4] = (_Float16)b1.x; h1[5] = (_Float16)b1.y;
      h1[6] = (_Float16)b1.z; h1[7] = (_Float16)b1.w;
      bf0[kk] = __builtin_bit_cast(uint4, h0);
      bf1[kk] = __builtin_bit_cast(uint4, h1);
    }
  }

  const uint4* ap = (const uint4*)qfrag;  // COALESCED: idx = (mt*8+kk)*64 + l
  const float inv_t = 1.0f / TEMP;
  int rr = l >> 2, qq = l & 3;           // stats: 4 lanes per row

  auto load_af = [&](uint4* dst, int mtv) {
#pragma unroll
    for (int kk = 0; kk < 8; kk++)
      dst[kk] = ap[(size_t)(mtv * 8 + kk) * 64 + l];
  };

  auto body = [&](const uint4* af, int mt) {
    f32x4 acc0 = {0.f, 0.f, 0.f, 0.f}, acc1 = {0.f, 0.f, 0.f, 0.f};
#pragma unroll
    for (int kk = 0; kk < 8; kk++) {
      acc0 = __builtin_amdgcn_mfma_f32_16x16x32_f16(
          __builtin_bit_cast(half8, af[kk]), __builtin_bit_cast(half8, bf0[kk]),
          acc0, 0, 0, 0);
      acc1 = __builtin_amdgcn_mfma_f32_16x16x32_f16(
          __builtin_bit_cast(half8, af[kk]), __builtin_bit_cast(half8, bf1[kk]),
          acc1, 0, 0, 0);
    }
    // labels fill slice: 2 aligned nontemporal f32x4 stores per body
    __builtin_nontemporal_store(onev, lbl + (size_t)mt * 512 + tid);
    __builtin_nontemporal_store(onev, lbl + (size_t)mt * 512 + 256 + tid);
    // wave-private transpose bounce (no barrier; DS is in-order per wave)
#pragma unroll
    for (int j = 0; j < 4; j++) {
      otw[(g4 * 4 + j) * 36 + r] = acc0[j];
      otw[(g4 * 4 + j) * 36 + 16 + r] = acc1[j];
    }
    // logits: scalar dword stores, 2 rows x 32 cols per instr (coalesces clean)
#pragma unroll
    for (int i = 0; i < 8; i++) {
      int row2 = i * 2 + (l >> 5), col = l & 31;
      float v = otw[row2 * 36 + col];
      out[(size_t)(mt * 16 + row2) * LCOLS + 3 + nbase + w * 32 + col] =
          v * inv_t;
    }
    // stats: lane covers 8 cols of row rr; reduce over 4-lane group
    f32x4 s0 = *(const f32x4*)&otw[rr * 36 + qq * 8];
    f32x4 s1 = *(const f32x4*)&otw[rr * 36 + qq * 8 + 4];
    float pm = posmin[mt * 16 + rr];
    float s = s0.x + s0.y + s0.z + s0.w + s1.x + s1.y + s1.z + s1.w;
    float s2 = s0.x * s0.x + s0.y * s0.y + s0.z * s0.z + s0.w * s0.w +
               s1.x * s1.x + s1.y * s1.y + s1.z * s1.z + s1.w * s1.w;
    float mx = fmaxf(fmaxf(fmaxf(s0.x, s0.y), fmaxf(s0.z, s0.w)),
                     fmaxf(fmaxf(s1.x, s1.y), fmaxf(s1.z, s1.w)));
    float c = (s0.x > pm ? 1.f : 0.f) + (s0.y > pm ? 1.f : 0.f) +
              (s0.z > pm ? 1.f : 0.f) + (s0.w > pm ? 1.f : 0.f) +
              (s1.x > pm ? 1.f : 0.f) + (s1.y > pm ? 1.f : 0.f) +
              (s1.z > pm ? 1.f : 0.f) + (s1.w > pm ? 1.f : 0.f);
#pragma unroll
    for (int m = 1; m < 4; m <<= 1) {
      s += __shfl_xor(s, m, 64);
      s2 += __shfl_xor(s2, m, 64);
      c += __shfl_xor(c, m, 64);
      mx = fmaxf(mx, __shfl_xor(mx, m, 64));
    }
    if (qq == 0) {
      us4 p = {f2bf(s), f2bf(s2), f2bf(mx), f2bf(c)};
      // [group][row]: 16 lanes/wave write 128B contiguous
      *(us4*)&partials[((size_t)(blk * 4 + w) * 512 + mt * 16 + rr) * 4] = p;
    }
  };

  uint4 afA[8], afB[8];
  load_af(afA, 0);
#pragma unroll 1
  for (int mt2 = 0; mt2 < 16; mt2++) {
    int mt = mt2 * 2;
    load_af(afB, mt + 1);
    body(afA, mt);
    if (mt2 < 15) load_af(afA, mt + 2);
    body(afB, mt + 1);
  }
}

// combine 2048 bf16 partials per row -> score[:, 0:4]. 64 blocks x 8 rows.
__global__ __launch_bounds__(256) void kreduce(const unsigned short* __restrict__ partials,
                                               const float* __restrict__ spos,
                                               float* __restrict__ out) {
  int r0 = blockIdx.x * 8;
  int tid = threadIdx.x;
  float s[8], s2[8], mx[8], c[8];
#pragma unroll
  for (int j = 0; j < 8; j++) { s[j] = 0.f; s2[j] = 0.f; mx[j] = -2.f; c[j] = 0.f; }
  for (int g = tid; g < 2048; g += 256) {
    const unsigned short* pg = partials + ((size_t)g * 512 + r0) * 4;
#pragma unroll
    for (int j = 0; j < 8; j++) {
      us4 v = *(const us4*)(pg + j * 4);
      s[j] += bf2f(v.x); s2[j] += bf2f(v.y);
      mx[j] = fmaxf(mx[j], bf2f(v.z)); c[j] += bf2f(v.w);
    }
  }
#pragma unroll
  for (int j = 0; j < 8; j++) {
#pragma unroll
    for (int m = 1; m < 64; m <<= 1) {
      s[j] += __shfl_xor(s[j], m, 64);
      s2[j] += __shfl_xor(s2[j], m, 64);
      c[j] += __shfl_xor(c[j], m, 64);
      mx[j] = fmaxf(mx[j], __shfl_xor(mx[j], m, 64));
    }
  }
  __shared__ float red[4][8][4];
  int w = tid >> 6, l = tid & 63;
  if (l == 0) {
#pragma unroll
    for (int j = 0; j < 8; j++) {
      red[w][j][0] = s[j]; red[w][j][1] = s2[j];
      red[w][j][2] = c[j]; red[w][j][3] = mx[j];
    }
  }
  __syncthreads();
  if (tid < 8) {
    int row = r0 + tid;
    float S = 0.f, S2 = 0.f, C = 0.f, M = -2.f;
#pragma unroll
    for (int w2 = 0; w2 < 4; w2++) {
      S += red[w2][tid][0]; S2 += red[w2][tid][1];
      C += red[w2][tid][2]; M = fmaxf(M, red[w2][tid][3]);
    }
    float mean = S / (float)NKQ;
    float var = (S2 - S * S / (float)NKQ) / (float)(NKQ - 1);  // ddof=1
    float cp = 0.f;
#pragma unroll
    for (int j = 0; j < 3; j++) cp += (M > spos[row * 3 + j]) ? 1.f : 0.f;
    float* scr = out + OFF_SCORE + (size_t)row * 7;
    scr[0] = mean; scr[1] = var; scr[2] = C; scr[3] = cp;
  }
}

extern "C" void kernel_launch(void* const* d_in, const int* in_sizes, int n_in,
                              void* d_out, int out_size, void* d_ws, size_t ws_size,
                              hipStream_t stream) {
  const float* query = (const float*)d_in[0];
  const float* key_emb = (const float*)d_in[1];
  const float* queue = (const float*)d_in[2];
  float* out = (float*)d_out;
  _Float16* qfrag = (_Float16*)d_ws;
  float* posmin = (float*)((char*)d_ws + 786432);
  float* spos = (float*)((char*)d_ws + 788480);
  unsigned short* partials = (unsigned short*)((char*)d_ws + 1048576);

  kfused<<<1024, 256, 0, stream>>>(query, key_emb, out, qfrag, posmin, spos);
  kgemm<<<512, 256, 0, stream>>>(queue, qfrag, posmin, out, partials);
  kreduce<<<64, 256, 0, stream>>>(partials, spos, out);
}

// Round 15
// 80.896 us; speedup vs baseline: 1.6480x; 1.0908x over previous
//
#include <hip/hip_runtime.h>

#define NB 512
#define ND 256
#define NKQ 65536
#define LCOLS 65539            // 3 + 65536
#define QTAIL 64000            // 65536 - 1536
#define TEMP 0.07f

// d_out element offsets (f32)
#define OFF_LABELS 33555968ull // 512*65539
#define OFF_SCORE  67111936ull // 2*512*65539
#define OFF_QUEUE  67115520ull // OFF_SCORE + 512*7

typedef __attribute__((ext_vector_type(8))) _Float16 half8;
typedef __attribute__((ext_vector_type(4))) float f32x4;
typedef __attribute__((ext_vector_type(4))) unsigned short us4;

__device__ inline float wave_sum(float v) {
#pragma unroll
  for (int m = 1; m < 64; m <<= 1) v += __shfl_xor(v, m, 64);
  return v;
}
__device__ inline unsigned short f2bf(float x) {  // RNE f32->bf16
  union { float f; unsigned u; } v; v.f = x;
  unsigned r = (v.u + 0x7FFF + ((v.u >> 16) & 1)) >> 16;
  return (unsigned short)r;
}
__device__ inline float bf2f(unsigned short h) {
  union { unsigned u; float f; } v; v.u = ((unsigned)h) << 16;
  return v.f;
}

// ws layout (bytes):
// [0, 262144)          : fp16 normalized q in MFMA FRAGMENT ORDER
// [786432, 788480)     : pos_min[512]
// [788480, 794624)     : score_pos[512*3]
// [1048576, 9437184)   : stat partials bf16x4 [2048 groups][512 rows]

// Fused prep+pos, 1024 blocks (verbatim r13/r14).
__global__ __launch_bounds__(256) void kfused(const float* __restrict__ query,
                                              const float* __restrict__ key_emb,
                                              float* __restrict__ out,
                                              _Float16* __restrict__ qfrag,
                                              float* __restrict__ posmin,
                                              float* __restrict__ spos) {
  int blk = blockIdx.x;
  int w = threadIdx.x >> 6, l = threadIdx.x & 63;
  if (blk < 512) {
    int r = blk * 4 + w;  // 0..2047
    const float* src = (r < NB) ? (query + (size_t)r * ND)
                                : (key_emb + (size_t)(r - NB) * ND);
    float x0 = src[l], x1 = src[l + 64], x2 = src[l + 128], x3 = src[l + 192];
    float ss = wave_sum(x0 * x0 + x1 * x1 + x2 * x2 + x3 * x3);
    float sc = 1.0f / fmaxf(sqrtf(ss), 1e-12f);
    x0 *= sc; x1 *= sc; x2 *= sc; x3 *= sc;
    if (r < NB) {
      float xs[4] = {x0, x1, x2, x3};
      int mt = r >> 4, rr = r & 15;
#pragma unroll
      for (int i = 0; i < 4; i++) {
        int d = l + i * 64;
        int kk = d >> 5, g4 = (d >> 3) & 3, j = d & 7;
        qfrag[((size_t)(mt * 8 + kk) * 64 + g4 * 16 + rr) * 8 + j] =
            (_Float16)xs[i];
      }
    } else {
      float* dst = out + OFF_QUEUE + (size_t)(QTAIL + r - NB) * ND;
      dst[l] = x0; dst[l + 64] = x1; dst[l + 128] = x2; dst[l + 192] = x3;
    }
  } else {
    int b = blk - 512;  // q row
    __shared__ float qsh[256];
    __shared__ float sps[3];
    const float* src = (w == 0) ? query + (size_t)b * ND
                                : key_emb + (size_t)(3 * b + w - 1) * ND;
    float x0 = src[l], x1 = src[l + 64], x2 = src[l + 128], x3 = src[l + 192];
    float ss = wave_sum(x0 * x0 + x1 * x1 + x2 * x2 + x3 * x3);
    float sc = 1.0f / fmaxf(sqrtf(ss), 1e-12f);
    x0 *= sc; x1 *= sc; x2 *= sc; x3 *= sc;
    if (w == 0) {
      qsh[l] = x0; qsh[l + 64] = x1; qsh[l + 128] = x2; qsh[l + 192] = x3;
    }
    __syncthreads();
    if (w > 0) {
      float d = x0 * qsh[l] + x1 * qsh[l + 64] + x2 * qsh[l + 128] +
                x3 * qsh[l + 192];
      d = wave_sum(d);
      if (l == 0) sps[w - 1] = d;
    }
    __syncthreads();
    if (threadIdx.x == 0) {
      float s0 = sps[0], s1 = sps[1], s2 = sps[2];
      float* lg = out + (size_t)b * LCOLS;
      float* scr = out + OFF_SCORE + (size_t)b * 7;
      lg[0] = s0 / TEMP; lg[1] = s1 / TEMP; lg[2] = s2 / TEMP;
      scr[4] = s0; scr[5] = s1; scr[6] = s2;
      spos[b * 3 + 0] = s0; spos[b * 3 + 1] = s1; spos[b * 3 + 2] = s2;
      posmin[b] = fminf(s0, fminf(s1, s2));
    }
  }
}

// r14 kgemm + LDS-staged B fragments: Phase 0's coalesced queue read now also
// stages the panel into LDS (fp16, XOR-swizzled); Phase 1 builds bf from
// ds_read_b128 instead of 32 scattered 16-row global loads per wave.
__global__ __launch_bounds__(256) void kgemm(const float* __restrict__ queue,
                                             const _Float16* __restrict__ qfrag,
                                             const float* __restrict__ posmin,
                                             float* __restrict__ out,
                                             unsigned short* __restrict__ partials) {
  __shared__ __align__(16) unsigned short btile[128 * 256];  // 64KB fp16, swizzled
  __shared__ __align__(16) float ot[4][16 * 36];  // per-wave private regions
  int tid = threadIdx.x;
  int braw = (int)blockIdx.x;
  // XCD swizzle: adjacent column-blocks share an XCD L2 (512 % 8 == 0)
  int blk = (braw & 7) * 64 + (braw >> 3);
  int nbase = blk * 128;
  int w = tid >> 6, l = tid & 63;
  int r = l & 15, g4 = l >> 4;
  float* otw = ot[w];
  // this block's contiguous labels slice (aligned f32x4)
  f32x4* lbl = (f32x4*)(out + OFF_LABELS) + (size_t)braw * 16384;
  const f32x4 onev = {1.f, 1.f, 1.f, 1.f};

  // Phase 0: coalesced queue read -> FIFO copy + fp16 LDS stage (swizzled)
  const f32x4* qp = (const f32x4*)queue;
  f32x4* nq = (f32x4*)(out + OFF_QUEUE);
#pragma unroll
  for (int i = 0; i < 32; i++) {
    int idx = tid + i * 256;          // 128 rows * 64 f32x4
    int row = idx >> 6, c4 = idx & 63;
    int grow = nbase + row;
    f32x4 v = qp[(size_t)grow * 64 + c4];
    if (grow >= 1536)
      __builtin_nontemporal_store(v, nq + (size_t)(grow - 1536) * 64 + c4);
    union { uint2 u; _Float16 h[4]; } pk;
    pk.h[0] = (_Float16)v.x; pk.h[1] = (_Float16)v.y;
    pk.h[2] = (_Float16)v.z; pk.h[3] = (_Float16)v.w;
    int boff = row * 512 + ((c4 * 8) ^ ((row & 7) << 4));
    *(uint2*)((char*)btile + boff) = pk.u;
  }
  // labels remainder: 8388992 - 512*16384 = 384 f32x4, one per block 0..383
  if (braw < 384 && tid == 0)
    __builtin_nontemporal_store(onev,
                                (f32x4*)(out + OFF_LABELS) + 8388608 + braw);
  __syncthreads();  // once per kernel

  // Phase 1: per-wave B fragments from LDS (16 x ds_read_b128)
  uint4 bf0[8], bf1[8];
#pragma unroll
  for (int kk = 0; kk < 8; kk++) {
    int brow0 = w * 32 + r;
    int brow1 = brow0 + 16;
    int bo0 = brow0 * 512 + ((kk * 64 + g4 * 16) ^ ((brow0 & 7) << 4));
    int bo1 = brow1 * 512 + ((kk * 64 + g4 * 16) ^ ((brow1 & 7) << 4));
    bf0[kk] = *(const uint4*)((char*)btile + bo0);
    bf1[kk] = *(const uint4*)((char*)btile + bo1);
  }

  const uint4* ap = (const uint4*)qfrag;  // COALESCED: idx = (mt*8+kk)*64 + l
  const float inv_t = 1.0f / TEMP;
  int rr = l >> 2, qq = l & 3;           // stats: 4 lanes per row

  auto load_af = [&](uint4* dst, int mtv) {
#pragma unroll
    for (int kk = 0; kk < 8; kk++)
      dst[kk] = ap[(size_t)(mtv * 8 + kk) * 64 + l];
  };

  auto body = [&](const uint4* af, int mt) {
    f32x4 acc0 = {0.f, 0.f, 0.f, 0.f}, acc1 = {0.f, 0.f, 0.f, 0.f};
#pragma unroll
    for (int kk = 0; kk < 8; kk++) {
      acc0 = __builtin_amdgcn_mfma_f32_16x16x32_f16(
          __builtin_bit_cast(half8, af[kk]), __builtin_bit_cast(half8, bf0[kk]),
          acc0, 0, 0, 0);
      acc1 = __builtin_amdgcn_mfma_f32_16x16x32_f16(
          __builtin_bit_cast(half8, af[kk]), __builtin_bit_cast(half8, bf1[kk]),
          acc1, 0, 0, 0);
    }
    // labels fill slice: 2 aligned nontemporal f32x4 stores per body
    __builtin_nontemporal_store(onev, lbl + (size_t)mt * 512 + tid);
    __builtin_nontemporal_store(onev, lbl + (size_t)mt * 512 + 256 + tid);
    // wave-private transpose bounce (no barrier; DS is in-order per wave)
#pragma unroll
    for (int j = 0; j < 4; j++) {
      otw[(g4 * 4 + j) * 36 + r] = acc0[j];
      otw[(g4 * 4 + j) * 36 + 16 + r] = acc1[j];
    }
    // logits: scalar dword stores, 2 rows x 32 cols per instr (coalesces clean)
#pragma unroll
    for (int i = 0; i < 8; i++) {
      int row2 = i * 2 + (l >> 5), col = l & 31;
      float v = otw[row2 * 36 + col];
      out[(size_t)(mt * 16 + row2) * LCOLS + 3 + nbase + w * 32 + col] =
          v * inv_t;
    }
    // stats: lane covers 8 cols of row rr; reduce over 4-lane group
    f32x4 s0 = *(const f32x4*)&otw[rr * 36 + qq * 8];
    f32x4 s1 = *(const f32x4*)&otw[rr * 36 + qq * 8 + 4];
    float pm = posmin[mt * 16 + rr];
    float s = s0.x + s0.y + s0.z + s0.w + s1.x + s1.y + s1.z + s1.w;
    float s2 = s0.x * s0.x + s0.y * s0.y + s0.z * s0.z + s0.w * s0.w +
               s1.x * s1.x + s1.y * s1.y + s1.z * s1.z + s1.w * s1.w;
    float mx = fmaxf(fmaxf(fmaxf(s0.x, s0.y), fmaxf(s0.z, s0.w)),
                     fmaxf(fmaxf(s1.x, s1.y), fmaxf(s1.z, s1.w)));
    float c = (s0.x > pm ? 1.f : 0.f) + (s0.y > pm ? 1.f : 0.f) +
              (s0.z > pm ? 1.f : 0.f) + (s0.w > pm ? 1.f : 0.f) +
              (s1.x > pm ? 1.f : 0.f) + (s1.y > pm ? 1.f : 0.f) +
              (s1.z > pm ? 1.f : 0.f) + (s1.w > pm ? 1.f : 0.f);
#pragma unroll
    for (int m = 1; m < 4; m <<= 1) {
      s += __shfl_xor(s, m, 64);
      s2 += __shfl_xor(s2, m, 64);
      c += __shfl_xor(c, m, 64);
      mx = fmaxf(mx, __shfl_xor(mx, m, 64));
    }
    if (qq == 0) {
      us4 p = {f2bf(s), f2bf(s2), f2bf(mx), f2bf(c)};
      // [group][row]: 16 lanes/wave write 128B contiguous
      *(us4*)&partials[((size_t)(blk * 4 + w) * 512 + mt * 16 + rr) * 4] = p;
    }
  };

  uint4 afA[8], afB[8];
  load_af(afA, 0);
#pragma unroll 1
  for (int mt2 = 0; mt2 < 16; mt2++) {
    int mt = mt2 * 2;
    load_af(afB, mt + 1);
    body(afA, mt);
    if (mt2 < 15) load_af(afA, mt + 2);
    body(afB, mt + 1);
  }
}

// combine 2048 bf16 partials per row -> score[:, 0:4]. 64 blocks x 8 rows.
__global__ __launch_bounds__(256) void kreduce(const unsigned short* __restrict__ partials,
                                               const float* __restrict__ spos,
                                               float* __restrict__ out) {
  int r0 = blockIdx.x * 8;
  int tid = threadIdx.x;
  float s[8], s2[8], mx[8], c[8];
#pragma unroll
  for (int j = 0; j < 8; j++) { s[j] = 0.f; s2[j] = 0.f; mx[j] = -2.f; c[j] = 0.f; }
  for (int g = tid; g < 2048; g += 256) {
    const unsigned short* pg = partials + ((size_t)g * 512 + r0) * 4;
#pragma unroll
    for (int j = 0; j < 8; j++) {
      us4 v = *(const us4*)(pg + j * 4);
      s[j] += bf2f(v.x); s2[j] += bf2f(v.y);
      mx[j] = fmaxf(mx[j], bf2f(v.z)); c[j] += bf2f(v.w);
    }
  }
#pragma unroll
  for (int j = 0; j < 8; j++) {
#pragma unroll
    for (int m = 1; m < 64; m <<= 1) {
      s[j] += __shfl_xor(s[j], m, 64);
      s2[j] += __shfl_xor(s2[j], m, 64);
      c[j] += __shfl_xor(c[j], m, 64);
      mx[j] = fmaxf(mx[j], __shfl_xor(mx[j], m, 64));
    }
  }
  __shared__ float red[4][8][4];
  int w = tid >> 6, l = tid & 63;
  if (l == 0) {
#pragma unroll
    for (int j = 0; j < 8; j++) {
      red[w][j][0] = s[j]; red[w][j][1] = s2[j];
      red[w][j][2] = c[j]; red[w][j][3] = mx[j];
    }
  }
  __syncthreads();
  if (tid < 8) {
    int row = r0 + tid;
    float S = 0.f, S2 = 0.f, C = 0.f, M = -2.f;
#pragma unroll
    for (int w2 = 0; w2 < 4; w2++) {
      S += red[w2][tid][0]; S2 += red[w2][tid][1];
      C += red[w2][tid][2]; M = fmaxf(M, red[w2][tid][3]);
    }
    float mean = S / (float)NKQ;
    float var = (S2 - S * S / (float)NKQ) / (float)(NKQ - 1);  // ddof=1
    float cp = 0.f;
#pragma unroll
    for (int j = 0; j < 3; j++) cp += (M > spos[row * 3 + j]) ? 1.f : 0.f;
    float* scr = out + OFF_SCORE + (size_t)row * 7;
    scr[0] = mean; scr[1] = var; scr[2] = C; scr[3] = cp;
  }
}

extern "C" void kernel_launch(void* const* d_in, const int* in_sizes, int n_in,
                              void* d_out, int out_size, void* d_ws, size_t ws_size,
                              hipStream_t stream) {
  const float* query = (const float*)d_in[0];
  const float* key_emb = (const float*)d_in[1];
  const float* queue = (const float*)d_in[2];
  float* out = (float*)d_out;
  _Float16* qfrag = (_Float16*)d_ws;
  float* posmin = (float*)((char*)d_ws + 786432);
  float* spos = (float*)((char*)d_ws + 788480);
  unsigned short* partials = (unsigned short*)((char*)d_ws + 1048576);

  kfused<<<1024, 256, 0, stream>>>(query, key_emb, out, qfrag, posmin, spos);
  kgemm<<<512, 256, 0, stream>>>(queue, qfrag, posmin, out, partials);
  kreduce<<<64, 256, 0, stream>>>(partials, spos, out);
}